// Round 1
// baseline (635.895 us; speedup 1.0000x reference)
//
#include <hip/hip_runtime.h>

#define NNODES 50000
#define NEDGES 640000
#define D 128

// ---------------- CSR build (rebuilt every launch; ws is re-poisoned) ----------------

__global__ void k_hist(const int* __restrict__ dst, int* __restrict__ cnt) {
    int e = blockIdx.x * 256 + threadIdx.x;
    if (e < NEDGES) atomicAdd(&cnt[dst[e]], 1);
}

__global__ void k_scan1(const int* __restrict__ cnt, int* __restrict__ rp,
                        int* __restrict__ bsum) {
    __shared__ int s[256];
    int tid = threadIdx.x;
    int i = blockIdx.x * 256 + tid;
    int v = (i < NNODES) ? cnt[i] : 0;
    s[tid] = v;
    __syncthreads();
    for (int off = 1; off < 256; off <<= 1) {
        int t = (tid >= off) ? s[tid - off] : 0;
        __syncthreads();
        s[tid] += t;
        __syncthreads();
    }
    if (i < NNODES) rp[i] = s[tid] - v;  // exclusive within block
    if (tid == 255) bsum[blockIdx.x] = s[255];
}

__global__ void k_scan2(int* __restrict__ bsum, int nb) {
    __shared__ int s[256];
    int tid = threadIdx.x;
    int v = (tid < nb) ? bsum[tid] : 0;
    s[tid] = v;
    __syncthreads();
    for (int off = 1; off < 256; off <<= 1) {
        int t = (tid >= off) ? s[tid - off] : 0;
        __syncthreads();
        s[tid] += t;
        __syncthreads();
    }
    if (tid < nb) bsum[tid] = s[tid] - v;  // exclusive
}

__global__ void k_add(int* __restrict__ rp, const int* __restrict__ bsum) {
    int i = blockIdx.x * 256 + threadIdx.x;
    if (i < NNODES) rp[i] += bsum[blockIdx.x];
    if (i == 0) rp[NNODES] = NEDGES;  // total is a compile-time constant
}

__global__ void k_scatter(const int* __restrict__ src, const int* __restrict__ dst,
                          const int* __restrict__ rp, int* __restrict__ fill,
                          int* __restrict__ srcs) {
    int e = blockIdx.x * 256 + threadIdx.x;
    if (e < NEDGES) {
        int dn = dst[e];
        int p = rp[dn] + atomicAdd(&fill[dn], 1);
        srcs[p] = src[e];
    }
}

// ---------------- aggregation: z = (1+eps)*h + sum_{e: dst==v} h[src[e]] ----------------
// 8 nodes per 256-thread block; 32 lanes per node, float4 per lane (512B/row per edge).
__global__ void k_agg(const float* __restrict__ h, const int* __restrict__ rp,
                      const int* __restrict__ srcs, const float* __restrict__ epsp,
                      float* __restrict__ z) {
    int tid = threadIdx.x;
    int lane = tid & 31;
    int node = blockIdx.x * 8 + (tid >> 5);
    float sc = 1.0f + epsp[0];
    const float4* h4 = (const float4*)h;
    float4 a = h4[node * 32 + lane];
    float4 acc = make_float4(sc * a.x, sc * a.y, sc * a.z, sc * a.w);
    int beg = rp[node], end = rp[node + 1];
    for (int e = beg; e < end; ++e) {
        int s = srcs[e];
        float4 v = h4[s * 32 + lane];
        acc.x += v.x; acc.y += v.y; acc.z += v.z; acc.w += v.w;
    }
    ((float4*)z)[node * 32 + lane] = acc;
}

// ---------------- fused 2-layer MLP: hout = relu(relu(z@W1+b1)@W2+b2) ----------------
// 64-row tile per block, W staged in LDS in 64-col halves: 32KB + 32KB = 64KB LDS,
// 2 blocks/CU. Each thread computes a 4x8 output micro-tile in fp32 registers.
__launch_bounds__(256, 2)
__global__ void k_mlp(const float* __restrict__ z, const float* __restrict__ W1,
                      const float* __restrict__ b1, const float* __restrict__ W2,
                      const float* __restrict__ b2, float* __restrict__ hout) {
    __shared__ float zt[64 * 128];   // 32 KB: input tile, later reused for T
    __shared__ float wb[128 * 64];   // 32 KB: one 64-col half of W
    int tid = threadIdx.x;
    int row0 = blockIdx.x * 64;
    int ty = tid >> 4, tx = tid & 15;

    // load z tile (coalesced float4)
    for (int i = tid; i < 64 * 32; i += 256) {
        int r = i >> 5, c4 = i & 31;
        int grow = row0 + r;
        float4 v = (grow < NNODES) ? ((const float4*)z)[grow * 32 + c4]
                                   : make_float4(0.f, 0.f, 0.f, 0.f);
        *(float4*)&zt[r * 128 + c4 * 4] = v;
    }

    float accT[4][8];
    for (int half = 0; half < 2; ++half) {
        __syncthreads();  // zt load done / previous wb use done
        for (int i = tid; i < 128 * 16; i += 256) {
            int r = i >> 4, c4 = i & 15;
            *(float4*)&wb[r * 64 + c4 * 4] = ((const float4*)W1)[r * 32 + half * 16 + c4];
        }
        __syncthreads();
        float acc[4][4];
        #pragma unroll
        for (int r = 0; r < 4; ++r)
            #pragma unroll
            for (int c = 0; c < 4; ++c)
                acc[r][c] = b1[half * 64 + tx * 4 + c];
        for (int k0 = 0; k0 < 128; k0 += 4) {
            float4 a[4];
            #pragma unroll
            for (int r = 0; r < 4; ++r)
                a[r] = *(const float4*)&zt[(ty * 4 + r) * 128 + k0];
            #pragma unroll
            for (int kk = 0; kk < 4; ++kk) {
                float4 b = *(const float4*)&wb[(k0 + kk) * 64 + tx * 4];
                #pragma unroll
                for (int r = 0; r < 4; ++r) {
                    float av = kk == 0 ? a[r].x : kk == 1 ? a[r].y : kk == 2 ? a[r].z : a[r].w;
                    acc[r][0] += av * b.x; acc[r][1] += av * b.y;
                    acc[r][2] += av * b.z; acc[r][3] += av * b.w;
                }
            }
        }
        #pragma unroll
        for (int r = 0; r < 4; ++r)
            #pragma unroll
            for (int c = 0; c < 4; ++c)
                accT[r][half * 4 + c] = fmaxf(acc[r][c], 0.f);
    }

    // overwrite zt with T = relu(z@W1+b1)
    __syncthreads();
    #pragma unroll
    for (int r = 0; r < 4; ++r) {
        *(float4*)&zt[(ty * 4 + r) * 128 + tx * 4] =
            make_float4(accT[r][0], accT[r][1], accT[r][2], accT[r][3]);
        *(float4*)&zt[(ty * 4 + r) * 128 + 64 + tx * 4] =
            make_float4(accT[r][4], accT[r][5], accT[r][6], accT[r][7]);
    }

    float accH[4][8];
    for (int half = 0; half < 2; ++half) {
        __syncthreads();  // T writes done / previous wb use done
        for (int i = tid; i < 128 * 16; i += 256) {
            int r = i >> 4, c4 = i & 15;
            *(float4*)&wb[r * 64 + c4 * 4] = ((const float4*)W2)[r * 32 + half * 16 + c4];
        }
        __syncthreads();
        float acc[4][4];
        #pragma unroll
        for (int r = 0; r < 4; ++r)
            #pragma unroll
            for (int c = 0; c < 4; ++c)
                acc[r][c] = b2[half * 64 + tx * 4 + c];
        for (int k0 = 0; k0 < 128; k0 += 4) {
            float4 a[4];
            #pragma unroll
            for (int r = 0; r < 4; ++r)
                a[r] = *(const float4*)&zt[(ty * 4 + r) * 128 + k0];
            #pragma unroll
            for (int kk = 0; kk < 4; ++kk) {
                float4 b = *(const float4*)&wb[(k0 + kk) * 64 + tx * 4];
                #pragma unroll
                for (int r = 0; r < 4; ++r) {
                    float av = kk == 0 ? a[r].x : kk == 1 ? a[r].y : kk == 2 ? a[r].z : a[r].w;
                    acc[r][0] += av * b.x; acc[r][1] += av * b.y;
                    acc[r][2] += av * b.z; acc[r][3] += av * b.w;
                }
            }
        }
        #pragma unroll
        for (int r = 0; r < 4; ++r)
            #pragma unroll
            for (int c = 0; c < 4; ++c)
                accH[r][half * 4 + c] = fmaxf(acc[r][c], 0.f);
    }

    #pragma unroll
    for (int r = 0; r < 4; ++r) {
        int grow = row0 + ty * 4 + r;
        if (grow < NNODES) {
            *(float4*)&hout[grow * 128 + tx * 4] =
                make_float4(accH[r][0], accH[r][1], accH[r][2], accH[r][3]);
            *(float4*)&hout[grow * 128 + 64 + tx * 4] =
                make_float4(accH[r][4], accH[r][5], accH[r][6], accH[r][7]);
        }
    }
}

// ---------------- final: out = concat(x,h1,h2,h3) @ fw + fb  (K=512 as 4 chunks) ----------------
__launch_bounds__(256, 2)
__global__ void k_final(const float* __restrict__ x, const float* __restrict__ h1,
                        const float* __restrict__ h2, const float* __restrict__ h3,
                        const float* __restrict__ fw, const float* __restrict__ fb,
                        float* __restrict__ out) {
    __shared__ float at[64 * 128];
    __shared__ float wb[128 * 64];
    int tid = threadIdx.x;
    int row0 = blockIdx.x * 64;
    int ty = tid >> 4, tx = tid & 15;

    float acc[4][8];
    #pragma unroll
    for (int r = 0; r < 4; ++r) {
        #pragma unroll
        for (int half = 0; half < 2; ++half)
            #pragma unroll
            for (int c = 0; c < 4; ++c)
                acc[r][half * 4 + c] = fb[half * 64 + tx * 4 + c];
    }

    for (int ch = 0; ch < 4; ++ch) {
        const float* hs = (ch == 0) ? x : (ch == 1) ? h1 : (ch == 2) ? h2 : h3;
        __syncthreads();  // previous chunk's reads done before overwriting at/wb
        for (int i = tid; i < 64 * 32; i += 256) {
            int r = i >> 5, c4 = i & 31;
            int grow = row0 + r;
            float4 v = (grow < NNODES) ? ((const float4*)hs)[grow * 32 + c4]
                                       : make_float4(0.f, 0.f, 0.f, 0.f);
            *(float4*)&at[r * 128 + c4 * 4] = v;
        }
        for (int half = 0; half < 2; ++half) {
            if (half) __syncthreads();  // half0 compute done before wb overwrite
            for (int i = tid; i < 128 * 16; i += 256) {
                int r = i >> 4, c4 = i & 15;
                *(float4*)&wb[r * 64 + c4 * 4] =
                    ((const float4*)fw)[ch * 4096 + r * 32 + half * 16 + c4];
            }
            __syncthreads();
            for (int k0 = 0; k0 < 128; k0 += 4) {
                float4 a[4];
                #pragma unroll
                for (int r = 0; r < 4; ++r)
                    a[r] = *(const float4*)&at[(ty * 4 + r) * 128 + k0];
                #pragma unroll
                for (int kk = 0; kk < 4; ++kk) {
                    float4 b = *(const float4*)&wb[(k0 + kk) * 64 + tx * 4];
                    #pragma unroll
                    for (int r = 0; r < 4; ++r) {
                        float av = kk == 0 ? a[r].x : kk == 1 ? a[r].y : kk == 2 ? a[r].z : a[r].w;
                        acc[r][half * 4 + 0] += av * b.x; acc[r][half * 4 + 1] += av * b.y;
                        acc[r][half * 4 + 2] += av * b.z; acc[r][half * 4 + 3] += av * b.w;
                    }
                }
            }
        }
    }

    #pragma unroll
    for (int r = 0; r < 4; ++r) {
        int grow = row0 + ty * 4 + r;
        if (grow < NNODES) {
            *(float4*)&out[grow * 128 + tx * 4] =
                make_float4(acc[r][0], acc[r][1], acc[r][2], acc[r][3]);
            *(float4*)&out[grow * 128 + 64 + tx * 4] =
                make_float4(acc[r][4], acc[r][5], acc[r][6], acc[r][7]);
        }
    }
}

extern "C" void kernel_launch(void* const* d_in, const int* in_sizes, int n_in,
                              void* d_out, int out_size, void* d_ws, size_t ws_size,
                              hipStream_t stream) {
    const float* x   = (const float*)d_in[0];
    const int*   ei  = (const int*)d_in[1];   // (2, E): row0 = src, row1 = dst
    const float* W1  = (const float*)d_in[2];
    const float* b1  = (const float*)d_in[3];
    const float* W2  = (const float*)d_in[4];
    const float* b2  = (const float*)d_in[5];
    const float* eps = (const float*)d_in[6];
    const float* fw  = (const float*)d_in[7];
    const float* fb  = (const float*)d_in[8];
    float* out = (float*)d_out;

    const int* srcA = ei;
    const int* dstA = ei + NEDGES;

    // workspace carve-up (256B aligned)
    char* p = (char*)d_ws;
    size_t off = 0;
    auto take = [&](size_t bytes) {
        char* r = p + off;
        off = (off + bytes + 255) & ~(size_t)255;
        return r;
    };
    int* rp    = (int*)take((NNODES + 1) * sizeof(int));
    int* cnt   = (int*)take(NNODES * sizeof(int));
    int* fill  = (int*)take(NNODES * sizeof(int));
    int* bsum  = (int*)take(256 * sizeof(int));
    int* srcs  = (int*)take(NEDGES * sizeof(int));
    float* z   = (float*)take((size_t)NNODES * D * sizeof(float));
    float* h1  = (float*)take((size_t)NNODES * D * sizeof(float));
    float* h2  = (float*)take((size_t)NNODES * D * sizeof(float));
    float* h3  = (float*)take((size_t)NNODES * D * sizeof(float));
    (void)ws_size; (void)in_sizes; (void)n_in; (void)out_size;

    hipMemsetAsync(cnt, 0, NNODES * sizeof(int), stream);
    hipMemsetAsync(fill, 0, NNODES * sizeof(int), stream);

    int nb = (NNODES + 255) / 256;  // 196
    k_hist<<<(NEDGES + 255) / 256, 256, 0, stream>>>(dstA, cnt);
    k_scan1<<<nb, 256, 0, stream>>>(cnt, rp, bsum);
    k_scan2<<<1, 256, 0, stream>>>(bsum, nb);
    k_add<<<nb, 256, 0, stream>>>(rp, bsum);
    k_scatter<<<(NEDGES + 255) / 256, 256, 0, stream>>>(srcA, dstA, rp, fill, srcs);

    const float* hin = x;
    float* houts[3] = {h1, h2, h3};
    for (int l = 0; l < 3; ++l) {
        k_agg<<<NNODES / 8, 256, 0, stream>>>(hin, rp, srcs, eps + l, z);
        k_mlp<<<(NNODES + 63) / 64, 256, 0, stream>>>(
            z, W1 + l * D * D, b1 + l * D, W2 + l * D * D, b2 + l * D, houts[l]);
        hin = houts[l];
    }
    k_final<<<(NNODES + 63) / 64, 256, 0, stream>>>(x, h1, h2, h3, fw, fb, out);
}

// Round 2
// 371.552 us; speedup vs baseline: 1.7115x; 1.7115x over previous
//
#include <hip/hip_runtime.h>

#define NNODES 50000
#define NEDGES 640000
#define D 128

typedef unsigned short u16;
typedef unsigned int u32;
typedef __bf16 bf16x8 __attribute__((ext_vector_type(8)));
typedef float f32x4 __attribute__((ext_vector_type(4)));
union AB { uint4 u4; bf16x8 f; };

__device__ __forceinline__ u16 f2b(float f) {
    u32 u = __float_as_uint(f);
    return (u16)((u + 0x7fffu + ((u >> 16) & 1u)) >> 16);
}
__device__ __forceinline__ u32 pack2(float lo, float hi) {
    return (u32)f2b(lo) | ((u32)f2b(hi) << 16);
}
__device__ __forceinline__ float blo(u32 v) { return __uint_as_float(v << 16); }
__device__ __forceinline__ float bhi(u32 v) { return __uint_as_float(v & 0xffff0000u); }

// ---------------- CSR build (unchanged from round 1) ----------------

__global__ void k_hist(const int* __restrict__ dst, int* __restrict__ cnt) {
    int e = blockIdx.x * 256 + threadIdx.x;
    if (e < NEDGES) atomicAdd(&cnt[dst[e]], 1);
}

__global__ void k_scan1(const int* __restrict__ cnt, int* __restrict__ rp,
                        int* __restrict__ bsum) {
    __shared__ int s[256];
    int tid = threadIdx.x;
    int i = blockIdx.x * 256 + tid;
    int v = (i < NNODES) ? cnt[i] : 0;
    s[tid] = v;
    __syncthreads();
    for (int off = 1; off < 256; off <<= 1) {
        int t = (tid >= off) ? s[tid - off] : 0;
        __syncthreads();
        s[tid] += t;
        __syncthreads();
    }
    if (i < NNODES) rp[i] = s[tid] - v;
    if (tid == 255) bsum[blockIdx.x] = s[255];
}

__global__ void k_scan2(int* __restrict__ bsum, int nb) {
    __shared__ int s[256];
    int tid = threadIdx.x;
    int v = (tid < nb) ? bsum[tid] : 0;
    s[tid] = v;
    __syncthreads();
    for (int off = 1; off < 256; off <<= 1) {
        int t = (tid >= off) ? s[tid - off] : 0;
        __syncthreads();
        s[tid] += t;
        __syncthreads();
    }
    if (tid < nb) bsum[tid] = s[tid] - v;
}

__global__ void k_add(int* __restrict__ rp, const int* __restrict__ bsum) {
    int i = blockIdx.x * 256 + threadIdx.x;
    if (i < NNODES) rp[i] += bsum[blockIdx.x];
    if (i == 0) rp[NNODES] = NEDGES;
}

__global__ void k_scatter(const int* __restrict__ src, const int* __restrict__ dst,
                          const int* __restrict__ rp, int* __restrict__ fill,
                          int* __restrict__ srcs) {
    int e = blockIdx.x * 256 + threadIdx.x;
    if (e < NEDGES) {
        int dn = dst[e];
        int p = rp[dn] + atomicAdd(&fill[dn], 1);
        srcs[p] = src[e];
    }
}

// ---------------- weight prep: fp32 -> bf16 transposed ----------------
// wT[n*128+k] = W[k*128+n] per 128x128 matrix; fw split into 4 K-chunks.
__global__ void k_prep(const float* __restrict__ W1, const float* __restrict__ W2,
                       const float* __restrict__ fw, u16* __restrict__ wT1,
                       u16* __restrict__ wT2, u16* __restrict__ fwTc) {
    int idx = blockIdx.x * 256 + threadIdx.x;  // grid covers 4*16384
    if (idx < 3 * 16384) {
        int l = idx >> 14, r = idx & 16383, n = r >> 7, k = r & 127;
        wT1[idx] = f2b(W1[l * 16384 + k * 128 + n]);
        wT2[idx] = f2b(W2[l * 16384 + k * 128 + n]);
    }
    if (idx < 4 * 16384) {
        int ch = idx >> 14, r = idx & 16383, n = r >> 7, k = r & 127;
        fwTc[idx] = f2b(fw[(ch * 128 + k) * 128 + n]);
    }
}

// ---------------- x fp32 -> bf16 ----------------
__global__ void k_cvt(const float* __restrict__ x, u32* __restrict__ xb) {
    int i = blockIdx.x * 256 + threadIdx.x;  // NNODES*64 pairs
    if (i < NNODES * 64) {
        float2 v = ((const float2*)x)[i];
        xb[i] = pack2(v.x, v.y);
    }
}

// ---------------- aggregation (bf16 in/out, fp32 accumulate) ----------------
// one wave per node; lane handles elements 2l, 2l+1 (one dword).
__global__ void k_agg(const u32* __restrict__ h2, const int* __restrict__ rp,
                      const int* __restrict__ srcs, const float* __restrict__ epsp,
                      u32* __restrict__ z2) {
    int tid = threadIdx.x;
    int lane = tid & 63;
    int node = blockIdx.x * 4 + (tid >> 6);
    float sc = 1.0f + epsp[0];
    u32 sv = h2[node * 64 + lane];
    float ax = sc * blo(sv), ay = sc * bhi(sv);
    int e = rp[node], end = rp[node + 1];
    for (; e + 2 <= end; e += 2) {
        int s0 = srcs[e], s1 = srcs[e + 1];
        u32 v0 = h2[s0 * 64 + lane];
        u32 v1 = h2[s1 * 64 + lane];
        ax += blo(v0) + blo(v1);
        ay += bhi(v0) + bhi(v1);
    }
    if (e < end) {
        u32 v = h2[srcs[e] * 64 + lane];
        ax += blo(v);
        ay += bhi(v);
    }
    z2[node * 64 + lane] = pack2(ax, ay);
}

// ---------------- fused MLP via MFMA: H = relu(relu(A@W1+b1)@W2+b2) ----------------
// M-tile 128 (4 waves x 32 rows), A-frags from global, W staged in 32KB LDS
// (restaged for W2), T round-trips through 32KB LDS. 64KB LDS -> 2 blocks/CU.
__launch_bounds__(256, 2)
__global__ void k_mlp(const u16* __restrict__ A, const u16* __restrict__ wT1g,
                      const float* __restrict__ b1, const u16* __restrict__ wT2g,
                      const float* __restrict__ b2, u16* __restrict__ H) {
    __shared__ u16 wbuf[128 * 128];  // 32 KB
    __shared__ u16 Tb[128 * 128];    // 32 KB
    int tid = threadIdx.x;
    int wave = tid >> 6, lane = tid & 63, l16 = lane & 15, quad = lane >> 4;
    int r0 = blockIdx.x * 128 + wave * 32;

    // stage W1^T
    {
        const uint4* g = (const uint4*)wT1g;
        for (int i = tid; i < 2048; i += 256) ((uint4*)wbuf)[i] = g[i];
    }

    // A-fragments from global (rows have zero cross-wave reuse)
    AB a[2][4];
#pragma unroll
    for (int s = 0; s < 2; ++s) {
        int row = r0 + s * 16 + l16;
#pragma unroll
        for (int kb = 0; kb < 4; ++kb) {
            if (row < NNODES)
                a[s][kb].u4 = *(const uint4*)&A[row * 128 + kb * 32 + quad * 8];
            else
                a[s][kb].u4 = make_uint4(0, 0, 0, 0);
        }
    }
    __syncthreads();

    f32x4 acc[2][8];
#pragma unroll
    for (int col = 0; col < 8; ++col) {
        float bv = b1[col * 16 + l16];
        acc[0][col] = (f32x4){bv, bv, bv, bv};
        acc[1][col] = (f32x4){bv, bv, bv, bv};
    }
#pragma unroll
    for (int col = 0; col < 8; ++col) {
#pragma unroll
        for (int kb = 0; kb < 4; ++kb) {
            AB b;
            b.u4 = *(const uint4*)&wbuf[(col * 16 + l16) * 128 + kb * 32 + quad * 8];
            acc[0][col] = __builtin_amdgcn_mfma_f32_16x16x32_bf16(a[0][kb].f, b.f, acc[0][col], 0, 0, 0);
            acc[1][col] = __builtin_amdgcn_mfma_f32_16x16x32_bf16(a[1][kb].f, b.f, acc[1][col], 0, 0, 0);
        }
    }

    // T = relu(.) -> LDS in bf16 (C-layout -> memory row-major)
#pragma unroll
    for (int s = 0; s < 2; ++s)
#pragma unroll
        for (int col = 0; col < 8; ++col)
#pragma unroll
            for (int r = 0; r < 4; ++r) {
                float v = fmaxf(acc[s][col][r], 0.f);
                Tb[(wave * 32 + s * 16 + quad * 4 + r) * 128 + col * 16 + l16] = f2b(v);
            }
    __syncthreads();

    // stage W2^T (overwrite wbuf)
    {
        const uint4* g = (const uint4*)wT2g;
        for (int i = tid; i < 2048; i += 256) ((uint4*)wbuf)[i] = g[i];
    }
    // a2 frags from own strip (written before the barrier above)
    AB a2[2][4];
#pragma unroll
    for (int s = 0; s < 2; ++s)
#pragma unroll
        for (int kb = 0; kb < 4; ++kb)
            a2[s][kb].u4 = *(const uint4*)&Tb[(wave * 32 + s * 16 + l16) * 128 + kb * 32 + quad * 8];
    __syncthreads();

#pragma unroll
    for (int col = 0; col < 8; ++col) {
        float bv = b2[col * 16 + l16];
        acc[0][col] = (f32x4){bv, bv, bv, bv};
        acc[1][col] = (f32x4){bv, bv, bv, bv};
    }
#pragma unroll
    for (int col = 0; col < 8; ++col) {
#pragma unroll
        for (int kb = 0; kb < 4; ++kb) {
            AB b;
            b.u4 = *(const uint4*)&wbuf[(col * 16 + l16) * 128 + kb * 32 + quad * 8];
            acc[0][col] = __builtin_amdgcn_mfma_f32_16x16x32_bf16(a2[0][kb].f, b.f, acc[0][col], 0, 0, 0);
            acc[1][col] = __builtin_amdgcn_mfma_f32_16x16x32_bf16(a2[1][kb].f, b.f, acc[1][col], 0, 0, 0);
        }
    }
    // relu -> bf16 -> own rows of Tb (in-order per wave; no cross-wave readers)
#pragma unroll
    for (int s = 0; s < 2; ++s)
#pragma unroll
        for (int col = 0; col < 8; ++col)
#pragma unroll
            for (int r = 0; r < 4; ++r) {
                float v = fmaxf(acc[s][col][r], 0.f);
                Tb[(wave * 32 + s * 16 + quad * 4 + r) * 128 + col * 16 + l16] = f2b(v);
            }
    __syncthreads();

    // coalesced copy Tb -> H
    for (int i = tid; i < 2048; i += 256) {
        int r = i >> 4, c = i & 15;
        int grow = blockIdx.x * 128 + r;
        if (grow < NNODES)
            *(uint4*)&H[grow * 128 + c * 8] = *(const uint4*)&Tb[r * 128 + c * 8];
    }
}

// ---------------- final: out = concat(x,h1,h2,h3) @ fw + fb, fp32 out ----------------
__launch_bounds__(256, 2)
__global__ void k_final(const u16* __restrict__ xb, const u16* __restrict__ h1,
                        const u16* __restrict__ h2b, const u16* __restrict__ h3,
                        const u16* __restrict__ fwTc, const float* __restrict__ fb,
                        float* __restrict__ out) {
    __shared__ u16 wbuf[128 * 128];  // 32 KB
    int tid = threadIdx.x;
    int wave = tid >> 6, lane = tid & 63, l16 = lane & 15, quad = lane >> 4;
    int r0 = blockIdx.x * 128 + wave * 32;

    f32x4 acc[2][8];
#pragma unroll
    for (int col = 0; col < 8; ++col) {
        float bv = fb[col * 16 + l16];
        acc[0][col] = (f32x4){bv, bv, bv, bv};
        acc[1][col] = (f32x4){bv, bv, bv, bv};
    }

    const u16* chin[4] = {xb, h1, h2b, h3};
    for (int ch = 0; ch < 4; ++ch) {
        __syncthreads();  // prior chunk's wbuf reads done before overwrite
        {
            const uint4* g = (const uint4*)(fwTc + ch * 16384);
            for (int i = tid; i < 2048; i += 256) ((uint4*)wbuf)[i] = g[i];
        }
        const u16* cp = chin[ch];
        AB a[2][4];
#pragma unroll
        for (int s = 0; s < 2; ++s) {
            int row = r0 + s * 16 + l16;
#pragma unroll
            for (int kb = 0; kb < 4; ++kb) {
                if (row < NNODES)
                    a[s][kb].u4 = *(const uint4*)&cp[row * 128 + kb * 32 + quad * 8];
                else
                    a[s][kb].u4 = make_uint4(0, 0, 0, 0);
            }
        }
        __syncthreads();
#pragma unroll
        for (int col = 0; col < 8; ++col) {
#pragma unroll
            for (int kb = 0; kb < 4; ++kb) {
                AB b;
                b.u4 = *(const uint4*)&wbuf[(col * 16 + l16) * 128 + kb * 32 + quad * 8];
                acc[0][col] = __builtin_amdgcn_mfma_f32_16x16x32_bf16(a[0][kb].f, b.f, acc[0][col], 0, 0, 0);
                acc[1][col] = __builtin_amdgcn_mfma_f32_16x16x32_bf16(a[1][kb].f, b.f, acc[1][col], 0, 0, 0);
            }
        }
    }

    // fp32 stores: 16 consecutive lanes -> 64B contiguous
#pragma unroll
    for (int s = 0; s < 2; ++s)
#pragma unroll
        for (int col = 0; col < 8; ++col)
#pragma unroll
            for (int r = 0; r < 4; ++r) {
                int row = r0 + s * 16 + quad * 4 + r;
                if (row < NNODES) out[row * 128 + col * 16 + l16] = acc[s][col][r];
            }
}

extern "C" void kernel_launch(void* const* d_in, const int* in_sizes, int n_in,
                              void* d_out, int out_size, void* d_ws, size_t ws_size,
                              hipStream_t stream) {
    const float* x   = (const float*)d_in[0];
    const int*   ei  = (const int*)d_in[1];
    const float* W1  = (const float*)d_in[2];
    const float* b1  = (const float*)d_in[3];
    const float* W2  = (const float*)d_in[4];
    const float* b2  = (const float*)d_in[5];
    const float* eps = (const float*)d_in[6];
    const float* fw  = (const float*)d_in[7];
    const float* fb  = (const float*)d_in[8];
    float* out = (float*)d_out;

    const int* srcA = ei;
    const int* dstA = ei + NEDGES;

    char* p = (char*)d_ws;
    size_t off = 0;
    auto take = [&](size_t bytes) {
        char* r = p + off;
        off = (off + bytes + 255) & ~(size_t)255;
        return r;
    };
    int* rp   = (int*)take((NNODES + 1) * sizeof(int));
    int* cnt  = (int*)take(NNODES * sizeof(int));
    int* fill = (int*)take(NNODES * sizeof(int));
    int* bsum = (int*)take(256 * sizeof(int));
    int* srcs = (int*)take(NEDGES * sizeof(int));
    u16* wT1  = (u16*)take(3 * 16384 * sizeof(u16));
    u16* wT2  = (u16*)take(3 * 16384 * sizeof(u16));
    u16* fwTc = (u16*)take(4 * 16384 * sizeof(u16));
    u16* xb   = (u16*)take((size_t)NNODES * D * sizeof(u16));
    u16* zb   = (u16*)take((size_t)NNODES * D * sizeof(u16));
    u16* hb1  = (u16*)take((size_t)NNODES * D * sizeof(u16));
    u16* hb2  = (u16*)take((size_t)NNODES * D * sizeof(u16));
    u16* hb3  = (u16*)take((size_t)NNODES * D * sizeof(u16));
    (void)ws_size; (void)in_sizes; (void)n_in; (void)out_size;

    hipMemsetAsync(cnt, 0, NNODES * sizeof(int), stream);
    hipMemsetAsync(fill, 0, NNODES * sizeof(int), stream);

    k_prep<<<(4 * 16384 + 255) / 256, 256, 0, stream>>>(W1, W2, fw, wT1, wT2, fwTc);
    k_cvt<<<(NNODES * 64 + 255) / 256, 256, 0, stream>>>(x, (u32*)xb);

    int nb = (NNODES + 255) / 256;
    k_hist<<<(NEDGES + 255) / 256, 256, 0, stream>>>(dstA, cnt);
    k_scan1<<<nb, 256, 0, stream>>>(cnt, rp, bsum);
    k_scan2<<<1, 256, 0, stream>>>(bsum, nb);
    k_add<<<nb, 256, 0, stream>>>(rp, bsum);
    k_scatter<<<(NEDGES + 255) / 256, 256, 0, stream>>>(srcA, dstA, rp, fill, srcs);

    const u16* hin = xb;
    u16* houts[3] = {hb1, hb2, hb3};
    int gm = (NNODES + 127) / 128;  // 391
    for (int l = 0; l < 3; ++l) {
        k_agg<<<NNODES / 4, 256, 0, stream>>>((const u32*)hin, rp, srcs, eps + l, (u32*)zb);
        k_mlp<<<gm, 256, 0, stream>>>(zb, wT1 + l * 16384, b1 + l * D,
                                      wT2 + l * 16384, b2 + l * D, houts[l]);
        hin = houts[l];
    }
    k_final<<<gm, 256, 0, stream>>>(xb, hb1, hb2, hb3, fwTc, fb, out);
}

// Round 3
// 319.861 us; speedup vs baseline: 1.9880x; 1.1616x over previous
//
#include <hip/hip_runtime.h>

#define NNODES 50000
#define NEDGES 640000
#define D 128

typedef unsigned short u16;
typedef unsigned int u32;
typedef __bf16 bf16x8 __attribute__((ext_vector_type(8)));
typedef float f32x4 __attribute__((ext_vector_type(4)));
union AB { uint4 u4; bf16x8 f; };

__device__ __forceinline__ u16 f2b(float f) {
    u32 u = __float_as_uint(f);
    return (u16)((u + 0x7fffu + ((u >> 16) & 1u)) >> 16);
}
__device__ __forceinline__ u32 pack2(float lo, float hi) {
    return (u32)f2b(lo) | ((u32)f2b(hi) << 16);
}
__device__ __forceinline__ float blo(u32 v) { return __uint_as_float(v << 16); }
__device__ __forceinline__ float bhi(u32 v) { return __uint_as_float(v & 0xffff0000u); }

// ---------------- CSR build ----------------

__global__ void k_hist(const int* __restrict__ dst, int* __restrict__ cnt) {
    int e = blockIdx.x * 256 + threadIdx.x;
    if (e < NEDGES) atomicAdd(&cnt[dst[e]], 1);
}

__global__ void k_scan1(const int* __restrict__ cnt, int* __restrict__ rp,
                        int* __restrict__ bsum) {
    __shared__ int s[256];
    int tid = threadIdx.x;
    int i = blockIdx.x * 256 + tid;
    int v = (i < NNODES) ? cnt[i] : 0;
    s[tid] = v;
    __syncthreads();
    for (int off = 1; off < 256; off <<= 1) {
        int t = (tid >= off) ? s[tid - off] : 0;
        __syncthreads();
        s[tid] += t;
        __syncthreads();
    }
    if (i < NNODES) rp[i] = s[tid] - v;
    if (tid == 255) bsum[blockIdx.x] = s[255];
}

__global__ void k_scan2(int* __restrict__ bsum, int nb) {
    __shared__ int s[256];
    int tid = threadIdx.x;
    int v = (tid < nb) ? bsum[tid] : 0;
    s[tid] = v;
    __syncthreads();
    for (int off = 1; off < 256; off <<= 1) {
        int t = (tid >= off) ? s[tid - off] : 0;
        __syncthreads();
        s[tid] += t;
        __syncthreads();
    }
    if (tid < nb) bsum[tid] = s[tid] - v;
}

__global__ void k_add(int* __restrict__ rp, const int* __restrict__ bsum) {
    int i = blockIdx.x * 256 + threadIdx.x;
    if (i < NNODES) rp[i] += bsum[blockIdx.x];
    if (i == 0) rp[NNODES] = NEDGES;
}

__global__ void k_scatter(const int* __restrict__ src, const int* __restrict__ dst,
                          const int* __restrict__ rp, int* __restrict__ fill,
                          int* __restrict__ srcs) {
    int e = blockIdx.x * 256 + threadIdx.x;
    if (e < NEDGES) {
        int dn = dst[e];
        int p = rp[dn] + atomicAdd(&fill[dn], 1);
        srcs[p] = src[e];
    }
}

// ---------------- weight prep: fp32 -> bf16 transposed ----------------
__global__ void k_prep(const float* __restrict__ W1, const float* __restrict__ W2,
                       const float* __restrict__ fw, u16* __restrict__ wT1,
                       u16* __restrict__ wT2, u16* __restrict__ fwTc) {
    int idx = blockIdx.x * 256 + threadIdx.x;
    if (idx < 3 * 16384) {
        int l = idx >> 14, r = idx & 16383, n = r >> 7, k = r & 127;
        wT1[idx] = f2b(W1[l * 16384 + k * 128 + n]);
        wT2[idx] = f2b(W2[l * 16384 + k * 128 + n]);
    }
    if (idx < 4 * 16384) {
        int ch = idx >> 14, r = idx & 16383, n = r >> 7, k = r & 127;
        fwTc[idx] = f2b(fw[(ch * 128 + k) * 128 + n]);
    }
}

__global__ void k_cvt(const float* __restrict__ x, u32* __restrict__ xb) {
    int i = blockIdx.x * 256 + threadIdx.x;
    if (i < NNODES * 64) {
        float2 v = ((const float2*)x)[i];
        xb[i] = pack2(v.x, v.y);
    }
}

// ---------------- aggregation: 16 lanes/node, batched index loads, 4-deep gather ----------------
__global__ void k_agg(const uint4* __restrict__ h4, const int* __restrict__ rp,
                      const int* __restrict__ srcs, const float* __restrict__ epsp,
                      uint4* __restrict__ z4) {
    int tid = threadIdx.x;
    int c = tid & 15;                               // 16B chunk within the 256B row
    int node = (blockIdx.x * 256 + tid) >> 4;       // 16 nodes per block (grid exact)
    int gbase = tid & 48;                           // group's base lane within wave (16-aligned)
    float sc = 1.0f + epsp[0];

    uint4 sv = h4[node * 16 + c];
    float acc[8];
    acc[0] = sc * blo(sv.x); acc[1] = sc * bhi(sv.x);
    acc[2] = sc * blo(sv.y); acc[3] = sc * bhi(sv.y);
    acc[4] = sc * blo(sv.z); acc[5] = sc * bhi(sv.z);
    acc[6] = sc * blo(sv.w); acc[7] = sc * bhi(sv.w);

    int beg = rp[node], end = rp[node + 1];
    for (int base = beg; base < end; base += 16) {
        int n = end - base; if (n > 16) n = 16;
        // one latency round of index loads per 16 edges
        int myidx = (base + c < end) ? srcs[base + c] : 0;
        int j = 0;
        for (; j + 4 <= n; j += 4) {
            int s0 = __shfl(myidx, gbase + j + 0, 64);
            int s1 = __shfl(myidx, gbase + j + 1, 64);
            int s2 = __shfl(myidx, gbase + j + 2, 64);
            int s3 = __shfl(myidx, gbase + j + 3, 64);
            uint4 v0 = h4[s0 * 16 + c];
            uint4 v1 = h4[s1 * 16 + c];
            uint4 v2 = h4[s2 * 16 + c];
            uint4 v3 = h4[s3 * 16 + c];
            acc[0] += blo(v0.x) + blo(v1.x) + blo(v2.x) + blo(v3.x);
            acc[1] += bhi(v0.x) + bhi(v1.x) + bhi(v2.x) + bhi(v3.x);
            acc[2] += blo(v0.y) + blo(v1.y) + blo(v2.y) + blo(v3.y);
            acc[3] += bhi(v0.y) + bhi(v1.y) + bhi(v2.y) + bhi(v3.y);
            acc[4] += blo(v0.z) + blo(v1.z) + blo(v2.z) + blo(v3.z);
            acc[5] += bhi(v0.z) + bhi(v1.z) + bhi(v2.z) + bhi(v3.z);
            acc[6] += blo(v0.w) + blo(v1.w) + blo(v2.w) + blo(v3.w);
            acc[7] += bhi(v0.w) + bhi(v1.w) + bhi(v2.w) + bhi(v3.w);
        }
        for (; j < n; ++j) {
            int s0 = __shfl(myidx, gbase + j, 64);
            uint4 v0 = h4[s0 * 16 + c];
            acc[0] += blo(v0.x); acc[1] += bhi(v0.x);
            acc[2] += blo(v0.y); acc[3] += bhi(v0.y);
            acc[4] += blo(v0.z); acc[5] += bhi(v0.z);
            acc[6] += blo(v0.w); acc[7] += bhi(v0.w);
        }
    }

    uint4 o;
    o.x = pack2(acc[0], acc[1]);
    o.y = pack2(acc[2], acc[3]);
    o.z = pack2(acc[4], acc[5]);
    o.w = pack2(acc[6], acc[7]);
    z4[node * 16 + c] = o;
}

// ---------------- fused MLP via MFMA (unchanged from round 2) ----------------
__launch_bounds__(256, 2)
__global__ void k_mlp(const u16* __restrict__ A, const u16* __restrict__ wT1g,
                      const float* __restrict__ b1, const u16* __restrict__ wT2g,
                      const float* __restrict__ b2, u16* __restrict__ H) {
    __shared__ u16 wbuf[128 * 128];
    __shared__ u16 Tb[128 * 128];
    int tid = threadIdx.x;
    int wave = tid >> 6, lane = tid & 63, l16 = lane & 15, quad = lane >> 4;
    int r0 = blockIdx.x * 128 + wave * 32;

    {
        const uint4* g = (const uint4*)wT1g;
        for (int i = tid; i < 2048; i += 256) ((uint4*)wbuf)[i] = g[i];
    }

    AB a[2][4];
#pragma unroll
    for (int s = 0; s < 2; ++s) {
        int row = r0 + s * 16 + l16;
#pragma unroll
        for (int kb = 0; kb < 4; ++kb) {
            if (row < NNODES)
                a[s][kb].u4 = *(const uint4*)&A[row * 128 + kb * 32 + quad * 8];
            else
                a[s][kb].u4 = make_uint4(0, 0, 0, 0);
        }
    }
    __syncthreads();

    f32x4 acc[2][8];
#pragma unroll
    for (int col = 0; col < 8; ++col) {
        float bv = b1[col * 16 + l16];
        acc[0][col] = (f32x4){bv, bv, bv, bv};
        acc[1][col] = (f32x4){bv, bv, bv, bv};
    }
#pragma unroll
    for (int col = 0; col < 8; ++col) {
#pragma unroll
        for (int kb = 0; kb < 4; ++kb) {
            AB b;
            b.u4 = *(const uint4*)&wbuf[(col * 16 + l16) * 128 + kb * 32 + quad * 8];
            acc[0][col] = __builtin_amdgcn_mfma_f32_16x16x32_bf16(a[0][kb].f, b.f, acc[0][col], 0, 0, 0);
            acc[1][col] = __builtin_amdgcn_mfma_f32_16x16x32_bf16(a[1][kb].f, b.f, acc[1][col], 0, 0, 0);
        }
    }

#pragma unroll
    for (int s = 0; s < 2; ++s)
#pragma unroll
        for (int col = 0; col < 8; ++col)
#pragma unroll
            for (int r = 0; r < 4; ++r) {
                float v = fmaxf(acc[s][col][r], 0.f);
                Tb[(wave * 32 + s * 16 + quad * 4 + r) * 128 + col * 16 + l16] = f2b(v);
            }
    __syncthreads();

    {
        const uint4* g = (const uint4*)wT2g;
        for (int i = tid; i < 2048; i += 256) ((uint4*)wbuf)[i] = g[i];
    }
    AB a2[2][4];
#pragma unroll
    for (int s = 0; s < 2; ++s)
#pragma unroll
        for (int kb = 0; kb < 4; ++kb)
            a2[s][kb].u4 = *(const uint4*)&Tb[(wave * 32 + s * 16 + l16) * 128 + kb * 32 + quad * 8];
    __syncthreads();

#pragma unroll
    for (int col = 0; col < 8; ++col) {
        float bv = b2[col * 16 + l16];
        acc[0][col] = (f32x4){bv, bv, bv, bv};
        acc[1][col] = (f32x4){bv, bv, bv, bv};
    }
#pragma unroll
    for (int col = 0; col < 8; ++col) {
#pragma unroll
        for (int kb = 0; kb < 4; ++kb) {
            AB b;
            b.u4 = *(const uint4*)&wbuf[(col * 16 + l16) * 128 + kb * 32 + quad * 8];
            acc[0][col] = __builtin_amdgcn_mfma_f32_16x16x32_bf16(a2[0][kb].f, b.f, acc[0][col], 0, 0, 0);
            acc[1][col] = __builtin_amdgcn_mfma_f32_16x16x32_bf16(a2[1][kb].f, b.f, acc[1][col], 0, 0, 0);
        }
    }
#pragma unroll
    for (int s = 0; s < 2; ++s)
#pragma unroll
        for (int col = 0; col < 8; ++col)
#pragma unroll
            for (int r = 0; r < 4; ++r) {
                float v = fmaxf(acc[s][col][r], 0.f);
                Tb[(wave * 32 + s * 16 + quad * 4 + r) * 128 + col * 16 + l16] = f2b(v);
            }
    __syncthreads();

    for (int i = tid; i < 2048; i += 256) {
        int r = i >> 4, cc = i & 15;
        int grow = blockIdx.x * 128 + r;
        if (grow < NNODES)
            *(uint4*)&H[grow * 128 + cc * 8] = *(const uint4*)&Tb[r * 128 + cc * 8];
    }
}

// ---------------- final projection (unchanged from round 2) ----------------
__launch_bounds__(256, 2)
__global__ void k_final(const u16* __restrict__ xb, const u16* __restrict__ h1,
                        const u16* __restrict__ h2b, const u16* __restrict__ h3,
                        const u16* __restrict__ fwTc, const float* __restrict__ fb,
                        float* __restrict__ out) {
    __shared__ u16 wbuf[128 * 128];
    int tid = threadIdx.x;
    int wave = tid >> 6, lane = tid & 63, l16 = lane & 15, quad = lane >> 4;
    int r0 = blockIdx.x * 128 + wave * 32;

    f32x4 acc[2][8];
#pragma unroll
    for (int col = 0; col < 8; ++col) {
        float bv = fb[col * 16 + l16];
        acc[0][col] = (f32x4){bv, bv, bv, bv};
        acc[1][col] = (f32x4){bv, bv, bv, bv};
    }

    const u16* chin[4] = {xb, h1, h2b, h3};
    for (int ch = 0; ch < 4; ++ch) {
        __syncthreads();
        {
            const uint4* g = (const uint4*)(fwTc + ch * 16384);
            for (int i = tid; i < 2048; i += 256) ((uint4*)wbuf)[i] = g[i];
        }
        const u16* cp = chin[ch];
        AB a[2][4];
#pragma unroll
        for (int s = 0; s < 2; ++s) {
            int row = r0 + s * 16 + l16;
#pragma unroll
            for (int kb = 0; kb < 4; ++kb) {
                if (row < NNODES)
                    a[s][kb].u4 = *(const uint4*)&cp[row * 128 + kb * 32 + quad * 8];
                else
                    a[s][kb].u4 = make_uint4(0, 0, 0, 0);
            }
        }
        __syncthreads();
#pragma unroll
        for (int col = 0; col < 8; ++col) {
#pragma unroll
            for (int kb = 0; kb < 4; ++kb) {
                AB b;
                b.u4 = *(const uint4*)&wbuf[(col * 16 + l16) * 128 + kb * 32 + quad * 8];
                acc[0][col] = __builtin_amdgcn_mfma_f32_16x16x32_bf16(a[0][kb].f, b.f, acc[0][col], 0, 0, 0);
                acc[1][col] = __builtin_amdgcn_mfma_f32_16x16x32_bf16(a[1][kb].f, b.f, acc[1][col], 0, 0, 0);
            }
        }
    }

#pragma unroll
    for (int s = 0; s < 2; ++s)
#pragma unroll
        for (int col = 0; col < 8; ++col)
#pragma unroll
            for (int r = 0; r < 4; ++r) {
                int row = r0 + s * 16 + quad * 4 + r;
                if (row < NNODES) out[row * 128 + col * 16 + l16] = acc[s][col][r];
            }
}

extern "C" void kernel_launch(void* const* d_in, const int* in_sizes, int n_in,
                              void* d_out, int out_size, void* d_ws, size_t ws_size,
                              hipStream_t stream) {
    const float* x   = (const float*)d_in[0];
    const int*   ei  = (const int*)d_in[1];
    const float* W1  = (const float*)d_in[2];
    const float* b1  = (const float*)d_in[3];
    const float* W2  = (const float*)d_in[4];
    const float* b2  = (const float*)d_in[5];
    const float* eps = (const float*)d_in[6];
    const float* fw  = (const float*)d_in[7];
    const float* fb  = (const float*)d_in[8];
    float* out = (float*)d_out;

    const int* srcA = ei;
    const int* dstA = ei + NEDGES;

    char* p = (char*)d_ws;
    size_t off = 0;
    auto take = [&](size_t bytes) {
        char* r = p + off;
        off = (off + bytes + 255) & ~(size_t)255;
        return r;
    };
    int* rp   = (int*)take((NNODES + 1) * sizeof(int));
    int* cnt  = (int*)take(NNODES * sizeof(int));
    int* fill = (int*)take(NNODES * sizeof(int));
    int* bsum = (int*)take(256 * sizeof(int));
    int* srcs = (int*)take(NEDGES * sizeof(int));
    u16* wT1  = (u16*)take(3 * 16384 * sizeof(u16));
    u16* wT2  = (u16*)take(3 * 16384 * sizeof(u16));
    u16* fwTc = (u16*)take(4 * 16384 * sizeof(u16));
    u16* xb   = (u16*)take((size_t)NNODES * D * sizeof(u16));
    u16* zb   = (u16*)take((size_t)NNODES * D * sizeof(u16));
    u16* hb1  = (u16*)take((size_t)NNODES * D * sizeof(u16));
    u16* hb2  = (u16*)take((size_t)NNODES * D * sizeof(u16));
    u16* hb3  = (u16*)take((size_t)NNODES * D * sizeof(u16));
    (void)ws_size; (void)in_sizes; (void)n_in; (void)out_size;

    hipMemsetAsync(cnt, 0, NNODES * sizeof(int), stream);
    hipMemsetAsync(fill, 0, NNODES * sizeof(int), stream);

    k_prep<<<(4 * 16384 + 255) / 256, 256, 0, stream>>>(W1, W2, fw, wT1, wT2, fwTc);
    k_cvt<<<(NNODES * 64 + 255) / 256, 256, 0, stream>>>(x, (u32*)xb);

    int nb = (NNODES + 255) / 256;
    k_hist<<<(NEDGES + 255) / 256, 256, 0, stream>>>(dstA, cnt);
    k_scan1<<<nb, 256, 0, stream>>>(cnt, rp, bsum);
    k_scan2<<<1, 256, 0, stream>>>(bsum, nb);
    k_add<<<nb, 256, 0, stream>>>(rp, bsum);
    k_scatter<<<(NEDGES + 255) / 256, 256, 0, stream>>>(srcA, dstA, rp, fill, srcs);

    const u16* hin = xb;
    u16* houts[3] = {hb1, hb2, hb3};
    int gm = (NNODES + 127) / 128;
    for (int l = 0; l < 3; ++l) {
        k_agg<<<NNODES * 16 / 256, 256, 0, stream>>>((const uint4*)hin, rp, srcs, eps + l, (uint4*)zb);
        k_mlp<<<gm, 256, 0, stream>>>(zb, wT1 + l * 16384, b1 + l * D,
                                      wT2 + l * 16384, b2 + l * D, houts[l]);
        hin = houts[l];
    }
    k_final<<<gm, 256, 0, stream>>>(xb, hb1, hb2, hb3, fwTc, fb, out);
}